// Round 22
// baseline (169.019 us; speedup 1.0000x reference)
//
#include <hip/hip_runtime.h>

typedef __bf16 bf16;
typedef __bf16 bf16x4 __attribute__((ext_vector_type(4)));
typedef __bf16 bf16x8 __attribute__((ext_vector_type(8)));
typedef float f32x4 __attribute__((ext_vector_type(4)));

#define MFMA_16x16x32(a, b, c) __builtin_amdgcn_mfma_f32_16x16x32_bf16((a), (b), (c), 0, 0, 0)

#define B_ 8
#define N_ 1024
#define C_ 768
#define H_ 12
#define HD_ 64
#define KDIM 768

__device__ __forceinline__ void gload_lds16(const void* g, void* l) {
  __builtin_amdgcn_global_load_lds(
      (const __attribute__((address_space(1))) void*)g,
      (__attribute__((address_space(3))) void*)l, 16, 0, 0);
}

// ---------------------------------------------------------------------------
// mask dtype detection (robust to int8/int32/int64 storage)
// ---------------------------------------------------------------------------
__global__ __launch_bounds__(256) void detect_mask_kernel(const unsigned* __restrict__ m32,
                                                          int* __restrict__ flags) {
  const int i = blockIdx.x * 256 + threadIdx.x;
  if (i < 2048) {
    const unsigned v = m32[i];
    if (v > 1u) atomicOr(&flags[0], 1);
    if ((i & 1) && v != 0u) atomicOr(&flags[1], 1);
  }
}

// ---------------------------------------------------------------------------
// cvt (balanced grid-stride): f32 -> bf16 for x|wq|wp as one flat range of
// float4 jobs; bias on first 8192 global threads.
// ---------------------------------------------------------------------------
__global__ __launch_bounds__(256) void cvt_kernel(const float* __restrict__ x,
                                                  const float* __restrict__ wq,
                                                  const float* __restrict__ wp,
                                                  const float* __restrict__ size_in,
                                                  const void* __restrict__ mask_raw,
                                                  const int* __restrict__ flags,
                                                  bf16* __restrict__ xb,
                                                  bf16* __restrict__ wqb,
                                                  bf16* __restrict__ wpb,
                                                  float* __restrict__ biasb) {
  const int tid = blockIdx.x * 256 + threadIdx.x;   // 2048*256 = 524288 thr
  if (tid < B_ * N_) {
    int mv;
    if (flags[0]) {
      mv = (int)((const unsigned char*)mask_raw)[tid];
    } else if (flags[1]) {
      mv = ((const int*)mask_raw)[tid];
    } else {  // int64
      const unsigned* m32 = (const unsigned*)mask_raw;
      mv = (int)(m32[2 * tid] | m32[2 * tid + 1]);
    }
    biasb[tid] = mv ? -1e30f : logf(size_in[tid]);
  }
  for (int i = tid; i < 2162688; i += 524288) {
    const float* src;
    bf16* dst;
    int j = i;
    if (j < 1572864) {
      src = x; dst = xb;
    } else if (j < 2015232) {
      j -= 1572864; src = wq; dst = wqb;
    } else {
      j -= 2015232; src = wp; dst = wpb;
    }
    const float4 v = ((const float4*)src)[j];
    bf16x4 o = {(bf16)v.x, (bf16)v.y, (bf16)v.z, (bf16)v.w};
    ((bf16x4*)dst)[j] = o;
  }
}

// ---------------------------------------------------------------------------
// GEMM (NT): out[m][o] = sum_k A[m][k] * W[o][k].  M=8192, K=768.
// R22: 128x128 tile, BK=32 -> 32KB LDS -> FIVE blocks/CU (launch_bounds
// (256,5)); grid 1152 fully resident. 2-deep counted-vmcnt schedule (R21):
//   compute buf[kt&1] -> s_barrier -> STAGE(kt+2 -> buf[kt&1]) ->
//   s_waitcnt vmcnt(4) (tile kt+1 landed; kt+2 in flight) -> s_barrier.
// Latency hiding now comes from 5-way block TLP (waves of other blocks run
// while this block waits). Rows are 64B = 4 slots; bank swizzle uses the
// involution slot ^= (row>>1)&3 (parity bit EXCLUDED -- R17's bug), audited
// to the 8-access/bank minimum. Pre-swizzled global source (G21).
// MODE 0: A linear [m][768]; scatter epilogue into q/k/vt
// MODE 1: A in [b][h][n][64]; f32 epilogue (BK=32: head=st>>1, off=(st&1)*32)
// ---------------------------------------------------------------------------
template <int MODE>
__global__ __launch_bounds__(256, 5) void gemm_bt(const bf16* __restrict__ A,
                                                  const bf16* __restrict__ W,
                                                  const float* __restrict__ bias,
                                                  bf16* __restrict__ out0,
                                                  bf16* __restrict__ out1,
                                                  bf16* __restrict__ out2,
                                                  float* __restrict__ outf) {
  __shared__ bf16 As[2][128 * 32];   // 2 x 8KB
  __shared__ bf16 Bs[2][128 * 32];   // 2 x 8KB
  const int bid = blockIdx.x;
  const int mt = bid % 64;
  const int nt = bid / 64;
  const int t = threadIdx.x;
  const int lane = t & 63, w = t >> 6;
  const int wm = w >> 1, wn = w & 1;
  const int l15 = lane & 15, lg = lane >> 4;

  f32x4 acc[4][4] = {};

  const int srow = t >> 2;                             // 0..63 (row in chunk)
  const int skel = ((t & 3) ^ ((srow >> 1) & 3)) * 8;  // pre-swizzled src slot
  const bf16* Ag = A + (size_t)(mt * 128) * KDIM;
  const bf16* Bg = W + (size_t)(nt * 128) * KDIM;
  const int bA = mt >> 3;              // MODE 1: batch of this M-tile
  const int nbase = (mt & 7) * 128;    // MODE 1: n-base of this M-tile

#define ASRC(st, c)                                                           \
  ((MODE == 0)                                                                \
       ? (Ag + (size_t)((c) * 64 + srow) * KDIM + (st) * 32 + skel)           \
       : (A + (((size_t)(bA * 12 + ((st) >> 1)) * 1024) + nbase + (c) * 64 +  \
               srow) * 64 + ((st) & 1) * 32 + skel))
#define BSRC(st, c) (Bg + (size_t)((c) * 64 + srow) * KDIM + (st) * 32 + skel)

  // stage K-tile st (4 x 16B wave-instrs: A c0,c1 + B c0,c1) into buffer buf
#define STAGE(st, buf)                                                        \
  {                                                                           \
    _Pragma("unroll") for (int c = 0; c < 2; ++c) {                           \
      gload_lds16(ASRC(st, c), (char*)As[buf] + c * 4096 + w * 1024);         \
      gload_lds16(BSRC(st, c), (char*)Bs[buf] + c * 4096 + w * 1024);         \
    }                                                                         \
  }

  // prologue: tiles 0 and 1 in flight (8 loads); wait for tile 0 only
  STAGE(0, 0);
  STAGE(1, 1);
  asm volatile("s_waitcnt vmcnt(4)" ::: "memory");
  __builtin_amdgcn_s_barrier();

  const int rsl = (lg ^ ((l15 >> 1) & 3)) * 8;  // reader phys-slot (elems)

  for (int kt = 0; kt < KDIM / 32; ++kt) {
    const int cur = kt & 1;
    bf16x8 af[4], bfr[4];
#pragma unroll
    for (int i = 0; i < 4; ++i)
      af[i] = *(const bf16x8*)(As[cur] + (wm * 64 + i * 16 + l15) * 32 + rsl);
#pragma unroll
    for (int j = 0; j < 4; ++j)
      bfr[j] = *(const bf16x8*)(Bs[cur] + (wn * 64 + j * 16 + l15) * 32 + rsl);
#pragma unroll
    for (int i = 0; i < 4; ++i)
#pragma unroll
      for (int j = 0; j < 4; ++j)
        acc[i][j] = MFMA_16x16x32(af[i], bfr[j], acc[i][j]);

    __builtin_amdgcn_s_barrier();   // all waves done reading buf[cur]
    if (kt < KDIM / 32 - 2) {
      STAGE(kt + 2, cur);                               // 8 in flight
      asm volatile("s_waitcnt vmcnt(4)" ::: "memory");  // tile kt+1 landed
    } else {
      asm volatile("s_waitcnt vmcnt(0)" ::: "memory");  // tail drain
    }
    __builtin_amdgcn_s_barrier();   // tile kt+1 visible to all threads
  }
#undef STAGE
#undef ASRC
#undef BSRC

  if (MODE == 0) {
    const int which = (nt * 128) / 768;  // 768 = 6*128, tiles never straddle
#pragma unroll
    for (int i = 0; i < 4; ++i)
#pragma unroll
      for (int j = 0; j < 4; ++j)
#pragma unroll
        for (int r = 0; r < 4; ++r) {
          const int m = mt * 128 + wm * 64 + i * 16 + lg * 4 + r;
          const int o = nt * 128 + wn * 64 + j * 16 + l15;
          const int b = m >> 10, n = m & 1023;
          const int f = o - which * 768;
          const int h = f >> 6, hd = f & 63;
          const bf16 bv = (bf16)acc[i][j][r];
          if (which == 0)
            out0[(((size_t)(b * 12 + h)) * 1024 + n) * 64 + hd] = bv;
          else if (which == 1)
            out1[(((size_t)(b * 12 + h)) * 1024 + n) * 64 + hd] = bv;
          else
            out2[(((size_t)(b * 12 + h)) * 64 + hd) * 1024 + n] = bv;
        }
  } else {
#pragma unroll
    for (int i = 0; i < 4; ++i)
#pragma unroll
      for (int j = 0; j < 4; ++j) {
        const int o = nt * 128 + wn * 64 + j * 16 + l15;
        const float bv = bias[o];
#pragma unroll
        for (int r = 0; r < 4; ++r) {
          const int m = mt * 128 + wm * 64 + i * 16 + lg * 4 + r;
          outf[(size_t)m * 768 + o] = acc[i][j][r] + bv;
        }
      }
  }
}

// ---------------------------------------------------------------------------
// k_mean (f32 out): kmean[b,n,hd] = mean_h k[b,h,n,hd]
// ---------------------------------------------------------------------------
__global__ __launch_bounds__(256) void kmean_kernel(const bf16* __restrict__ kbuf,
                                                    float* __restrict__ kmean) {
  const int i = blockIdx.x * 256 + threadIdx.x;
  if (i >= B_ * N_ * HD_) return;
  const int hd = i & 63;
  const int n = (i >> 6) & 1023;
  const int b = i >> 16;
  float s = 0.f;
#pragma unroll
  for (int h = 0; h < 12; ++h)
    s += (float)kbuf[(((size_t)(b * 12 + h)) * 1024 + n) * 64 + hd];
  kmean[i] = s * (1.0f / 12.0f);
}

// ---------------------------------------------------------------------------
// MFMA flash attention (R13-validated). Block = 8 waves (512 thr), each wave
// 2 q-tiles of 16 rows -> 256 q-rows/block; grid = 96 bh x 4 qt. Only FOUR
// blocks stream each bh's K/V -> HBM fetch floor ~111MB independent of the
// workgroup->XCD mapping. KBLK=64, double-buffered LDS K/V, swapped-operand
// QK^T, lane-local softmax, contiguous [b][h][n][64] store.
// ---------------------------------------------------------------------------
__global__ __launch_bounds__(512, 4) void attn_mfma(const bf16* __restrict__ qbuf,
                                                    const bf16* __restrict__ kbuf,
                                                    const bf16* __restrict__ vtbuf,
                                                    const float* __restrict__ biasb,
                                                    bf16* __restrict__ outws) {
  __shared__ bf16 Ks[2][4096];  // [64 rows][8 slots of 8 elems], swizzled
  __shared__ bf16 Vs[2][4096];
  const int id = blockIdx.x;
  const int qt = id & 3;
  const int bh = id >> 2;
  const int b = bh / 12;
  const int t = threadIdx.x, lane = t & 63, w = t >> 6;  // w 0..7
  const int l15 = lane & 15, lg = lane >> 4;
  const int qbase = qt * 256 + w * 16;   // tile0 rows; tile1 = qbase + 128

  const bf16* Q = qbuf + ((size_t)bh * 1024 + qbase) * 64;
  const bf16* Kp = kbuf + (size_t)bh * 65536;
  const bf16* Vt = vtbuf + (size_t)bh * 65536;
  const float* bias = biasb + b * 1024;

  // Q as B-operand: col=l15 (q-row), k-slots lg*8+e = d
  const bf16x8 qb0 = *(const bf16x8*)(Q + l15 * 64 + lg * 8);
  const bf16x8 qb1 = *(const bf16x8*)(Q + l15 * 64 + 32 + lg * 8);
  const bf16x8 qc0 = *(const bf16x8*)(Q + (128 + l15) * 64 + lg * 8);
  const bf16x8 qc1 = *(const bf16x8*)(Q + (128 + l15) * 64 + 32 + lg * 8);

  // staging: thread t fills LDS bytes [t*16, t*16+16) of each 8KB tile.
  // K row srow holds key pi(srow); phys slot (t&7) holds logical slot
  // (t&7)^(srow&7)  (bank swizzle via pre-swizzled source).
  const int srow = t >> 3;                 // 0..63
  const int dsl = (t & 7) ^ (srow & 7);
  const int kkey = 32 * ((srow >> 5) & 1) + 4 * ((srow >> 4) & 1) +
                   8 * ((srow >> 2) & 3) + (srow & 3);
  const bf16* srcK = Kp + kkey * 64 + dsl * 8;
  const bf16* srcV = Vt + (size_t)srow * 1024 + dsl * 8;

  gload_lds16(srcK, (char*)&Ks[0][0] + w * 1024);
  gload_lds16(srcV, (char*)&Vs[0][0] + w * 1024);
  __syncthreads();

  const int bb0 = 8 * lg;        // bias quad base (D-row=lg*4+j)
  const int swz = l15 & 7;

  f32x4 oacc[4] = {}, oacc2[4] = {};
  float m = -1e30f, l = 0.f;
  float m2 = -1e30f, l2 = 0.f;

  for (int kt = 0; kt < 16; ++kt) {
    const int cur = kt & 1;
    const int kb = kt * 64;
    if (kt < 15) {  // stage next tile into the other buffer
      gload_lds16(srcK + (size_t)(kb + 64) * 64, (char*)&Ks[cur ^ 1][0] + w * 1024);
      gload_lds16(srcV + (kb + 64), (char*)&Vs[cur ^ 1][0] + w * 1024);
    }

    const bf16* LK = Ks[cur];
    const bf16* LV = Vs[cur];
    float sv[4][4], sw[4][4];
#pragma unroll
    for (int f = 0; f < 4; ++f) {
      const int cf = 32 * (f >> 1) + 4 * (f & 1);
      const bf16* kj = LK + (f * 16 + l15) * 64;
      const bf16x8 ka0 = *(const bf16x8*)(kj + (lg ^ swz) * 8);
      const bf16x8 ka1 = *(const bf16x8*)(kj + ((lg + 4) ^ swz) * 8);
      f32x4 z = {}, y = {};
      z = MFMA_16x16x32(ka0, qb0, z);
      y = MFMA_16x16x32(ka0, qc0, y);
      z = MFMA_16x16x32(ka1, qb1, z);
      y = MFMA_16x16x32(ka1, qc1, y);
      const float4 bi = *(const float4*)(bias + kb + cf + bb0);
      sv[f][0] = z[0] * 0.125f + bi.x;
      sv[f][1] = z[1] * 0.125f + bi.y;
      sv[f][2] = z[2] * 0.125f + bi.z;
      sv[f][3] = z[3] * 0.125f + bi.w;
      sw[f][0] = y[0] * 0.125f + bi.x;
      sw[f][1] = y[1] * 0.125f + bi.y;
      sw[f][2] = y[2] * 0.125f + bi.z;
      sw[f][3] = y[3] * 0.125f + bi.w;
    }
    // per-tile max over 64 keys: 15 local + 2 shuffles each
    float mx = sv[0][0], mx2 = sw[0][0];
#pragma unroll
    for (int f = 0; f < 4; ++f)
#pragma unroll
      for (int j = 0; j < 4; ++j) {
        mx = fmaxf(mx, sv[f][j]);
        mx2 = fmaxf(mx2, sw[f][j]);
      }
    mx = fmaxf(mx, __shfl_xor(mx, 16, 64));
    mx = fmaxf(mx, __shfl_xor(mx, 32, 64));
    mx2 = fmaxf(mx2, __shfl_xor(mx2, 16, 64));
    mx2 = fmaxf(mx2, __shfl_xor(mx2, 32, 64));
    const float mn = fmaxf(m, mx);
    const float mn2 = fmaxf(m2, mx2);
    const float resc = __expf(m - mn);
    const float resc2 = __expf(m2 - mn2);
    m = mn;
    m2 = mn2;

    float rs = 0.f, rs2 = 0.f;
    bf16x8 pa0, pa1, pa2, pa3;
#pragma unroll
    for (int f = 0; f < 4; ++f)
#pragma unroll
      for (int j = 0; j < 4; ++j) {
        const float p = __expf(sv[f][j] - mn);
        const float p2 = __expf(sw[f][j] - mn2);
        rs += p;
        rs2 += p2;
        const bf16 pb = (bf16)p;
        const bf16 pb2 = (bf16)p2;
        if (f == 0) { pa0[j] = pb; pa2[j] = pb2; }
        else if (f == 1) { pa0[4 + j] = pb; pa2[4 + j] = pb2; }
        else if (f == 2) { pa1[j] = pb; pa3[j] = pb2; }
        else { pa1[4 + j] = pb; pa3[4 + j] = pb2; }
      }
    rs += __shfl_xor(rs, 16, 64);
    rs += __shfl_xor(rs, 32, 64);
    rs2 += __shfl_xor(rs2, 16, 64);
    rs2 += __shfl_xor(rs2, 32, 64);
    l = l * resc + rs;
    l2 = l2 * resc2 + rs2;

#pragma unroll
    for (int df = 0; df < 4; ++df) {
      const bf16* vj = LV + (df * 16 + l15) * 64;
      const bf16x8 va0 = *(const bf16x8*)(vj + (lg ^ swz) * 8);
      const bf16x8 va1 = *(const bf16x8*)(vj + ((lg + 4) ^ swz) * 8);
      f32x4 t4 = oacc[df];
      f32x4 u4 = oacc2[df];
#pragma unroll
      for (int j = 0; j < 4; ++j) {
        t4[j] *= resc;
        u4[j] *= resc2;
      }
      t4 = MFMA_16x16x32(va0, pa0, t4);
      u4 = MFMA_16x16x32(va0, pa2, u4);
      t4 = MFMA_16x16x32(va1, pa1, t4);
      u4 = MFMA_16x16x32(va1, pa3, u4);
      oacc[df] = t4;
      oacc2[df] = u4;
    }
    __syncthreads();  // drains vmcnt (stage t+1 done); frees buf[cur]
  }

  // contiguous store: attnw[b][h][n][64]; tile0 rows qbase.., tile1 +128
  const float inv = 1.0f / l;
  const float inv2 = 1.0f / l2;
  bf16* outp = outws + ((size_t)bh * 1024 + qbase + l15) * 64;
#pragma unroll
  for (int df = 0; df < 4; ++df) {
    bf16x4 ov = {(bf16)(oacc[df][0] * inv), (bf16)(oacc[df][1] * inv),
                 (bf16)(oacc[df][2] * inv), (bf16)(oacc[df][3] * inv)};
    *(bf16x4*)(outp + df * 16 + lg * 4) = ov;
    bf16x4 ov2 = {(bf16)(oacc2[df][0] * inv2), (bf16)(oacc2[df][1] * inv2),
                  (bf16)(oacc2[df][2] * inv2), (bf16)(oacc2[df][3] * inv2)};
    *(bf16x4*)(outp + (size_t)128 * 64 + df * 16 + lg * 4) = ov2;
  }
}

// ---------------------------------------------------------------------------
extern "C" void kernel_launch(void* const* d_in, const int* in_sizes, int n_in,
                              void* d_out, int out_size, void* d_ws, size_t ws_size,
                              hipStream_t stream) {
  const float* x       = (const float*)d_in[0];
  const float* size_in = (const float*)d_in[1];
  const void*  mask    = d_in[2];
  const float* w_qkv   = (const float*)d_in[3];
  const float* w_proj  = (const float*)d_in[4];
  const float* b_proj  = (const float*)d_in[5];
  float* out = (float*)d_out;   // f32 outputs per reference dtype

  if (n_in < 6 ||
      in_sizes[0] != 6291456 || in_sizes[1] != 8192 || in_sizes[2] != 8192 ||
      in_sizes[3] != 1769472 || in_sizes[4] != 589824 || in_sizes[5] != 768)
    return;

  const size_t QS = (size_t)B_ * H_ * N_ * HD_;  // 6291456 elems
  if (ws_size < 55083024) return;

  bf16* xb    = (bf16*)d_ws;       // dead after gemm<0>; reused as attnw
  bf16* qbuf  = xb + QS;
  bf16* kbuf  = qbuf + QS;
  bf16* vtbuf = kbuf + QS;
  bf16* wqb   = vtbuf + QS;        // 1769472 elems
  bf16* wpb   = wqb + 1769472;     // 589824 elems
  float* biasb = (float*)(wpb + 589824);
  int* flags = (int*)(biasb + 8192);
  bf16* attnw = xb;                // [b][h][n][64]

  hipMemsetAsync(flags, 0, 8, stream);
  detect_mask_kernel<<<8, 256, 0, stream>>>((const unsigned*)mask, flags);
  cvt_kernel<<<2048, 256, 0, stream>>>(x, w_qkv, w_proj, size_in, mask, flags,
                                       xb, wqb, wpb, biasb);
  gemm_bt<0><<<64 * 18, 256, 0, stream>>>(xb, wqb, nullptr, qbuf, kbuf, vtbuf, nullptr);
  kmean_kernel<<<2048, 256, 0, stream>>>(kbuf, out + (size_t)B_ * N_ * C_);
  attn_mfma<<<384, 512, 0, stream>>>(qbuf, kbuf, vtbuf, biasb, attnw);
  gemm_bt<1><<<64 * 6, 256, 0, stream>>>(attnw, wpb, b_proj, nullptr, nullptr, nullptr, out);
}

// Round 23
// 153.503 us; speedup vs baseline: 1.1011x; 1.1011x over previous
//
#include <hip/hip_runtime.h>

typedef __bf16 bf16;
typedef __bf16 bf16x4 __attribute__((ext_vector_type(4)));
typedef __bf16 bf16x8 __attribute__((ext_vector_type(8)));
typedef float f32x4 __attribute__((ext_vector_type(4)));

#define MFMA_16x16x32(a, b, c) __builtin_amdgcn_mfma_f32_16x16x32_bf16((a), (b), (c), 0, 0, 0)

#define B_ 8
#define N_ 1024
#define C_ 768
#define H_ 12
#define HD_ 64
#define KDIM 768

__device__ __forceinline__ void gload_lds16(const void* g, void* l) {
  __builtin_amdgcn_global_load_lds(
      (const __attribute__((address_space(1))) void*)g,
      (__attribute__((address_space(3))) void*)l, 16, 0, 0);
}

// ---------------------------------------------------------------------------
// mask dtype detection (robust to int8/int32/int64 storage)
// ---------------------------------------------------------------------------
__global__ __launch_bounds__(256) void detect_mask_kernel(const unsigned* __restrict__ m32,
                                                          int* __restrict__ flags) {
  const int i = blockIdx.x * 256 + threadIdx.x;
  if (i < 2048) {
    const unsigned v = m32[i];
    if (v > 1u) atomicOr(&flags[0], 1);
    if ((i & 1) && v != 0u) atomicOr(&flags[1], 1);
  }
}

// ---------------------------------------------------------------------------
// cvt (balanced grid-stride): f32 -> bf16 for x|wq|wp as one flat range of
// float4 jobs; bias on first 8192 global threads.
// ---------------------------------------------------------------------------
__global__ __launch_bounds__(256) void cvt_kernel(const float* __restrict__ x,
                                                  const float* __restrict__ wq,
                                                  const float* __restrict__ wp,
                                                  const float* __restrict__ size_in,
                                                  const void* __restrict__ mask_raw,
                                                  const int* __restrict__ flags,
                                                  bf16* __restrict__ xb,
                                                  bf16* __restrict__ wqb,
                                                  bf16* __restrict__ wpb,
                                                  float* __restrict__ biasb) {
  const int tid = blockIdx.x * 256 + threadIdx.x;   // 2048*256 = 524288 thr
  if (tid < B_ * N_) {
    int mv;
    if (flags[0]) {
      mv = (int)((const unsigned char*)mask_raw)[tid];
    } else if (flags[1]) {
      mv = ((const int*)mask_raw)[tid];
    } else {  // int64
      const unsigned* m32 = (const unsigned*)mask_raw;
      mv = (int)(m32[2 * tid] | m32[2 * tid + 1]);
    }
    biasb[tid] = mv ? -1e30f : logf(size_in[tid]);
  }
  for (int i = tid; i < 2162688; i += 524288) {
    const float* src;
    bf16* dst;
    int j = i;
    if (j < 1572864) {
      src = x; dst = xb;
    } else if (j < 2015232) {
      j -= 1572864; src = wq; dst = wqb;
    } else {
      j -= 2015232; src = wp; dst = wpb;
    }
    const float4 v = ((const float4*)src)[j];
    bf16x4 o = {(bf16)v.x, (bf16)v.y, (bf16)v.z, (bf16)v.w};
    ((bf16x4*)dst)[j] = o;
  }
}

// ---------------------------------------------------------------------------
// GEMM (NT): out[m][o] = sum_k A[m][k] * W[o][k].  M=8192, K=768.
// R21-best config: 128x128 tile, BK=64, two LDS buffers (64KB -> 2 blocks/CU),
// 2-deep counted-vmcnt pipeline:
//   compute buf[kt&1] -> s_barrier -> STAGE(kt+2 -> buf[kt&1]) ->
//   s_waitcnt vmcnt(8) (tile kt+1 landed; kt+2 in flight) -> s_barrier.
// R23 adds T5: s_setprio(1) around the MFMA cluster (2 co-resident blocks at
// different phases -> scheduler favors the MFMA-issuing waves). XOR bank
// swizzle both tiles (R15-measured SQ_LDS_BANK_CONFLICT = 0).
// MODE 0: A linear [m][768]; scatter epilogue into q/k/vt
// MODE 1: A in [b][h][n][64] layout (attnw); f32 epilogue outf = acc + bias
// ---------------------------------------------------------------------------
template <int MODE>
__global__ __launch_bounds__(256) void gemm_bt(const bf16* __restrict__ A,
                                               const bf16* __restrict__ W,
                                               const float* __restrict__ bias,
                                               bf16* __restrict__ out0,
                                               bf16* __restrict__ out1,
                                               bf16* __restrict__ out2,
                                               float* __restrict__ outf) {
  __shared__ bf16 As[2][128 * 64];
  __shared__ bf16 Bs[2][128 * 64];
  const int bid = blockIdx.x;
  const int mt = bid % 64;
  const int nt = bid / 64;
  const int t = threadIdx.x;
  const int lane = t & 63, w = t >> 6;
  const int wm = w >> 1, wn = w & 1;
  const int l15 = lane & 15, lg = lane >> 4;

  f32x4 acc[4][4] = {};

  const int srow = t >> 3;                        // row within 32-row chunk
  const int skel = ((t & 7) ^ (srow & 7)) * 8;    // pre-swizzled source slot
  const bf16* Ag = A + (size_t)(mt * 128) * KDIM;
  const bf16* Bg = W + (size_t)(nt * 128) * KDIM;
  const int bA = mt >> 3;              // MODE 1: batch of this M-tile
  const int nbase = (mt & 7) * 128;    // MODE 1: n-base of this M-tile

#define ASRC(st, c)                                                          \
  ((MODE == 0)                                                               \
       ? (Ag + (size_t)((c) * 32 + srow) * KDIM + (st) * 64 + skel)          \
       : (A + (((size_t)(bA * 12 + (st)) * 1024) + nbase + (c) * 32 + srow)  \
              * 64 + skel))
#define BSRC(st, c) (Bg + (size_t)((c) * 32 + srow) * KDIM + (st) * 64 + skel)

  // stage K-tile st (8 x 16B loads/thread) into buffer `buf`
#define STAGE(st, buf)                                                        \
  {                                                                           \
    _Pragma("unroll") for (int c = 0; c < 4; ++c) {                           \
      gload_lds16(ASRC(st, c), (char*)As[buf] + c * 4096 + w * 1024);         \
      gload_lds16(BSRC(st, c), (char*)Bs[buf] + c * 4096 + w * 1024);         \
    }                                                                         \
  }

  // prologue: tiles 0 and 1 in flight (16 loads); wait for tile 0 only
  STAGE(0, 0);
  STAGE(1, 1);
  asm volatile("s_waitcnt vmcnt(8)" ::: "memory");
  __builtin_amdgcn_s_barrier();

  const int swz = l15 & 7;   // reader-side swizzle (row&7 == l15&7)

  for (int kt = 0; kt < KDIM / 64; ++kt) {
    const int cur = kt & 1;
    __builtin_amdgcn_s_setprio(1);
#pragma unroll
    for (int ks = 0; ks < 2; ++ks) {
      bf16x8 af[4], bfr[4];
#pragma unroll
      for (int i = 0; i < 4; ++i)
        af[i] = *(const bf16x8*)(As[cur] + (wm * 64 + i * 16 + l15) * 64 +
                                 ((ks * 4 + lg) ^ swz) * 8);
#pragma unroll
      for (int i = 0; i < 4; ++i)
        bfr[i] = *(const bf16x8*)(Bs[cur] + (wn * 64 + i * 16 + l15) * 64 +
                                  ((ks * 4 + lg) ^ swz) * 8);
#pragma unroll
      for (int i = 0; i < 4; ++i)
#pragma unroll
        for (int j = 0; j < 4; ++j)
          acc[i][j] = MFMA_16x16x32(af[i], bfr[j], acc[i][j]);
    }
    __builtin_amdgcn_s_setprio(0);
    __builtin_amdgcn_s_barrier();   // all waves done reading buf[cur]
    if (kt < KDIM / 64 - 2) {
      STAGE(kt + 2, cur);                               // 16 in flight
      asm volatile("s_waitcnt vmcnt(8)" ::: "memory");  // tile kt+1 landed
    } else {
      asm volatile("s_waitcnt vmcnt(0)" ::: "memory");  // tail drain
    }
    __builtin_amdgcn_s_barrier();   // tile kt+1 visible to all threads
  }
#undef STAGE
#undef ASRC
#undef BSRC

  if (MODE == 0) {
    const int which = (nt * 128) / 768;  // 768 = 6*128, tiles never straddle
#pragma unroll
    for (int i = 0; i < 4; ++i)
#pragma unroll
      for (int j = 0; j < 4; ++j)
#pragma unroll
        for (int r = 0; r < 4; ++r) {
          const int m = mt * 128 + wm * 64 + i * 16 + lg * 4 + r;
          const int o = nt * 128 + wn * 64 + j * 16 + l15;
          const int b = m >> 10, n = m & 1023;
          const int f = o - which * 768;
          const int h = f >> 6, hd = f & 63;
          const bf16 bv = (bf16)acc[i][j][r];
          if (which == 0)
            out0[(((size_t)(b * 12 + h)) * 1024 + n) * 64 + hd] = bv;
          else if (which == 1)
            out1[(((size_t)(b * 12 + h)) * 1024 + n) * 64 + hd] = bv;
          else
            out2[(((size_t)(b * 12 + h)) * 64 + hd) * 1024 + n] = bv;
        }
  } else {
#pragma unroll
    for (int i = 0; i < 4; ++i)
#pragma unroll
      for (int j = 0; j < 4; ++j) {
        const int o = nt * 128 + wn * 64 + j * 16 + l15;
        const float bv = bias[o];
#pragma unroll
        for (int r = 0; r < 4; ++r) {
          const int m = mt * 128 + wm * 64 + i * 16 + lg * 4 + r;
          outf[(size_t)m * 768 + o] = acc[i][j][r] + bv;
        }
      }
  }
}

// ---------------------------------------------------------------------------
// k_mean (f32 out): kmean[b,n,hd] = mean_h k[b,h,n,hd]
// ---------------------------------------------------------------------------
__global__ __launch_bounds__(256) void kmean_kernel(const bf16* __restrict__ kbuf,
                                                    float* __restrict__ kmean) {
  const int i = blockIdx.x * 256 + threadIdx.x;
  if (i >= B_ * N_ * HD_) return;
  const int hd = i & 63;
  const int n = (i >> 6) & 1023;
  const int b = i >> 16;
  float s = 0.f;
#pragma unroll
  for (int h = 0; h < 12; ++h)
    s += (float)kbuf[(((size_t)(b * 12 + h)) * 1024 + n) * 64 + hd];
  kmean[i] = s * (1.0f / 12.0f);
}

// ---------------------------------------------------------------------------
// MFMA flash attention (R13-validated). Block = 8 waves (512 thr), each wave
// 2 q-tiles of 16 rows -> 256 q-rows/block; grid = 96 bh x 4 qt. Only FOUR
// blocks stream each bh's K/V -> HBM fetch floor ~111MB independent of the
// workgroup->XCD mapping. KBLK=64, double-buffered LDS K/V, swapped-operand
// QK^T, lane-local softmax, contiguous [b][h][n][64] store.
// ---------------------------------------------------------------------------
__global__ __launch_bounds__(512, 4) void attn_mfma(const bf16* __restrict__ qbuf,
                                                    const bf16* __restrict__ kbuf,
                                                    const bf16* __restrict__ vtbuf,
                                                    const float* __restrict__ biasb,
                                                    bf16* __restrict__ outws) {
  __shared__ bf16 Ks[2][4096];  // [64 rows][8 slots of 8 elems], swizzled
  __shared__ bf16 Vs[2][4096];
  const int id = blockIdx.x;
  const int qt = id & 3;
  const int bh = id >> 2;
  const int b = bh / 12;
  const int t = threadIdx.x, lane = t & 63, w = t >> 6;  // w 0..7
  const int l15 = lane & 15, lg = lane >> 4;
  const int qbase = qt * 256 + w * 16;   // tile0 rows; tile1 = qbase + 128

  const bf16* Q = qbuf + ((size_t)bh * 1024 + qbase) * 64;
  const bf16* Kp = kbuf + (size_t)bh * 65536;
  const bf16* Vt = vtbuf + (size_t)bh * 65536;
  const float* bias = biasb + b * 1024;

  // Q as B-operand: col=l15 (q-row), k-slots lg*8+e = d
  const bf16x8 qb0 = *(const bf16x8*)(Q + l15 * 64 + lg * 8);
  const bf16x8 qb1 = *(const bf16x8*)(Q + l15 * 64 + 32 + lg * 8);
  const bf16x8 qc0 = *(const bf16x8*)(Q + (128 + l15) * 64 + lg * 8);
  const bf16x8 qc1 = *(const bf16x8*)(Q + (128 + l15) * 64 + 32 + lg * 8);

  // staging: thread t fills LDS bytes [t*16, t*16+16) of each 8KB tile.
  // K row srow holds key pi(srow); phys slot (t&7) holds logical slot
  // (t&7)^(srow&7)  (bank swizzle via pre-swizzled source).
  const int srow = t >> 3;                 // 0..63
  const int dsl = (t & 7) ^ (srow & 7);
  const int kkey = 32 * ((srow >> 5) & 1) + 4 * ((srow >> 4) & 1) +
                   8 * ((srow >> 2) & 3) + (srow & 3);
  const bf16* srcK = Kp + kkey * 64 + dsl * 8;
  const bf16* srcV = Vt + (size_t)srow * 1024 + dsl * 8;

  gload_lds16(srcK, (char*)&Ks[0][0] + w * 1024);
  gload_lds16(srcV, (char*)&Vs[0][0] + w * 1024);
  __syncthreads();

  const int bb0 = 8 * lg;        // bias quad base (D-row=lg*4+j)
  const int swz = l15 & 7;

  f32x4 oacc[4] = {}, oacc2[4] = {};
  float m = -1e30f, l = 0.f;
  float m2 = -1e30f, l2 = 0.f;

  for (int kt = 0; kt < 16; ++kt) {
    const int cur = kt & 1;
    const int kb = kt * 64;
    if (kt < 15) {  // stage next tile into the other buffer
      gload_lds16(srcK + (size_t)(kb + 64) * 64, (char*)&Ks[cur ^ 1][0] + w * 1024);
      gload_lds16(srcV + (kb + 64), (char*)&Vs[cur ^ 1][0] + w * 1024);
    }

    const bf16* LK = Ks[cur];
    const bf16* LV = Vs[cur];
    float sv[4][4], sw[4][4];
#pragma unroll
    for (int f = 0; f < 4; ++f) {
      const int cf = 32 * (f >> 1) + 4 * (f & 1);
      const bf16* kj = LK + (f * 16 + l15) * 64;
      const bf16x8 ka0 = *(const bf16x8*)(kj + (lg ^ swz) * 8);
      const bf16x8 ka1 = *(const bf16x8*)(kj + ((lg + 4) ^ swz) * 8);
      f32x4 z = {}, y = {};
      z = MFMA_16x16x32(ka0, qb0, z);
      y = MFMA_16x16x32(ka0, qc0, y);
      z = MFMA_16x16x32(ka1, qb1, z);
      y = MFMA_16x16x32(ka1, qc1, y);
      const float4 bi = *(const float4*)(bias + kb + cf + bb0);
      sv[f][0] = z[0] * 0.125f + bi.x;
      sv[f][1] = z[1] * 0.125f + bi.y;
      sv[f][2] = z[2] * 0.125f + bi.z;
      sv[f][3] = z[3] * 0.125f + bi.w;
      sw[f][0] = y[0] * 0.125f + bi.x;
      sw[f][1] = y[1] * 0.125f + bi.y;
      sw[f][2] = y[2] * 0.125f + bi.z;
      sw[f][3] = y[3] * 0.125f + bi.w;
    }
    // per-tile max over 64 keys: 15 local + 2 shuffles each
    float mx = sv[0][0], mx2 = sw[0][0];
#pragma unroll
    for (int f = 0; f < 4; ++f)
#pragma unroll
      for (int j = 0; j < 4; ++j) {
        mx = fmaxf(mx, sv[f][j]);
        mx2 = fmaxf(mx2, sw[f][j]);
      }
    mx = fmaxf(mx, __shfl_xor(mx, 16, 64));
    mx = fmaxf(mx, __shfl_xor(mx, 32, 64));
    mx2 = fmaxf(mx2, __shfl_xor(mx2, 16, 64));
    mx2 = fmaxf(mx2, __shfl_xor(mx2, 32, 64));
    const float mn = fmaxf(m, mx);
    const float mn2 = fmaxf(m2, mx2);
    const float resc = __expf(m - mn);
    const float resc2 = __expf(m2 - mn2);
    m = mn;
    m2 = mn2;

    float rs = 0.f, rs2 = 0.f;
    bf16x8 pa0, pa1, pa2, pa3;
#pragma unroll
    for (int f = 0; f < 4; ++f)
#pragma unroll
      for (int j = 0; j < 4; ++j) {
        const float p = __expf(sv[f][j] - mn);
        const float p2 = __expf(sw[f][j] - mn2);
        rs += p;
        rs2 += p2;
        const bf16 pb = (bf16)p;
        const bf16 pb2 = (bf16)p2;
        if (f == 0) { pa0[j] = pb; pa2[j] = pb2; }
        else if (f == 1) { pa0[4 + j] = pb; pa2[4 + j] = pb2; }
        else if (f == 2) { pa1[j] = pb; pa3[j] = pb2; }
        else { pa1[4 + j] = pb; pa3[4 + j] = pb2; }
      }
    rs += __shfl_xor(rs, 16, 64);
    rs += __shfl_xor(rs, 32, 64);
    rs2 += __shfl_xor(rs2, 16, 64);
    rs2 += __shfl_xor(rs2, 32, 64);
    l = l * resc + rs;
    l2 = l2 * resc2 + rs2;

#pragma unroll
    for (int df = 0; df < 4; ++df) {
      const bf16* vj = LV + (df * 16 + l15) * 64;
      const bf16x8 va0 = *(const bf16x8*)(vj + (lg ^ swz) * 8);
      const bf16x8 va1 = *(const bf16x8*)(vj + ((lg + 4) ^ swz) * 8);
      f32x4 t4 = oacc[df];
      f32x4 u4 = oacc2[df];
#pragma unroll
      for (int j = 0; j < 4; ++j) {
        t4[j] *= resc;
        u4[j] *= resc2;
      }
      t4 = MFMA_16x16x32(va0, pa0, t4);
      u4 = MFMA_16x16x32(va0, pa2, u4);
      t4 = MFMA_16x16x32(va1, pa1, t4);
      u4 = MFMA_16x16x32(va1, pa3, u4);
      oacc[df] = t4;
      oacc2[df] = u4;
    }
    __syncthreads();  // drains vmcnt (stage t+1 done); frees buf[cur]
  }

  // contiguous store: attnw[b][h][n][64]; tile0 rows qbase.., tile1 +128
  const float inv = 1.0f / l;
  const float inv2 = 1.0f / l2;
  bf16* outp = outws + ((size_t)bh * 1024 + qbase + l15) * 64;
#pragma unroll
  for (int df = 0; df < 4; ++df) {
    bf16x4 ov = {(bf16)(oacc[df][0] * inv), (bf16)(oacc[df][1] * inv),
                 (bf16)(oacc[df][2] * inv), (bf16)(oacc[df][3] * inv)};
    *(bf16x4*)(outp + df * 16 + lg * 4) = ov;
    bf16x4 ov2 = {(bf16)(oacc2[df][0] * inv2), (bf16)(oacc2[df][1] * inv2),
                  (bf16)(oacc2[df][2] * inv2), (bf16)(oacc2[df][3] * inv2)};
    *(bf16x4*)(outp + (size_t)128 * 64 + df * 16 + lg * 4) = ov2;
  }
}

// ---------------------------------------------------------------------------
extern "C" void kernel_launch(void* const* d_in, const int* in_sizes, int n_in,
                              void* d_out, int out_size, void* d_ws, size_t ws_size,
                              hipStream_t stream) {
  const float* x       = (const float*)d_in[0];
  const float* size_in = (const float*)d_in[1];
  const void*  mask    = d_in[2];
  const float* w_qkv   = (const float*)d_in[3];
  const float* w_proj  = (const float*)d_in[4];
  const float* b_proj  = (const float*)d_in[5];
  float* out = (float*)d_out;   // f32 outputs per reference dtype

  if (n_in < 6 ||
      in_sizes[0] != 6291456 || in_sizes[1] != 8192 || in_sizes[2] != 8192 ||
      in_sizes[3] != 1769472 || in_sizes[4] != 589824 || in_sizes[5] != 768)
    return;

  const size_t QS = (size_t)B_ * H_ * N_ * HD_;  // 6291456 elems
  if (ws_size < 55083024) return;

  bf16* xb    = (bf16*)d_ws;       // dead after gemm<0>; reused as attnw
  bf16* qbuf  = xb + QS;
  bf16* kbuf  = qbuf + QS;
  bf16* vtbuf = kbuf + QS;
  bf16* wqb   = vtbuf + QS;        // 1769472 elems
  bf16* wpb   = wqb + 1769472;     // 589824 elems
  float* biasb = (float*)(wpb + 589824);
  int* flags = (int*)(biasb + 8192);
  bf16* attnw = xb;                // [b][h][n][64]

  hipMemsetAsync(flags, 0, 8, stream);
  detect_mask_kernel<<<8, 256, 0, stream>>>((const unsigned*)mask, flags);
  cvt_kernel<<<2048, 256, 0, stream>>>(x, w_qkv, w_proj, size_in, mask, flags,
                                       xb, wqb, wpb, biasb);
  gemm_bt<0><<<64 * 18, 256, 0, stream>>>(xb, wqb, nullptr, qbuf, kbuf, vtbuf, nullptr);
  kmean_kernel<<<2048, 256, 0, stream>>>(kbuf, out + (size_t)B_ * N_ * C_);
  attn_mfma<<<384, 512, 0, stream>>>(qbuf, kbuf, vtbuf, biasb, attnw);
  gemm_bt<1><<<64 * 6, 256, 0, stream>>>(attnw, wpb, b_proj, nullptr, nullptr, nullptr, out);
}

// Round 24
// 150.850 us; speedup vs baseline: 1.1204x; 1.0176x over previous
//
#include <hip/hip_runtime.h>

typedef __bf16 bf16;
typedef __bf16 bf16x4 __attribute__((ext_vector_type(4)));
typedef __bf16 bf16x8 __attribute__((ext_vector_type(8)));
typedef float f32x4 __attribute__((ext_vector_type(4)));

#define MFMA_16x16x32(a, b, c) __builtin_amdgcn_mfma_f32_16x16x32_bf16((a), (b), (c), 0, 0, 0)

#define B_ 8
#define N_ 1024
#define C_ 768
#define H_ 12
#define HD_ 64
#define KDIM 768

__device__ __forceinline__ void gload_lds16(const void* g, void* l) {
  __builtin_amdgcn_global_load_lds(
      (const __attribute__((address_space(1))) void*)g,
      (__attribute__((address_space(3))) void*)l, 16, 0, 0);
}

// ---------------------------------------------------------------------------
// mask dtype detection (robust to int8/int32/int64 storage)
// ---------------------------------------------------------------------------
__global__ __launch_bounds__(256) void detect_mask_kernel(const unsigned* __restrict__ m32,
                                                          int* __restrict__ flags) {
  const int i = blockIdx.x * 256 + threadIdx.x;
  if (i < 2048) {
    const unsigned v = m32[i];
    if (v > 1u) atomicOr(&flags[0], 1);
    if ((i & 1) && v != 0u) atomicOr(&flags[1], 1);
  }
}

// ---------------------------------------------------------------------------
// cvt (balanced grid-stride): f32 -> bf16 for x|wq|wp as one flat range of
// float4 jobs; bias on first 8192 global threads.
// ---------------------------------------------------------------------------
__global__ __launch_bounds__(256) void cvt_kernel(const float* __restrict__ x,
                                                  const float* __restrict__ wq,
                                                  const float* __restrict__ wp,
                                                  const float* __restrict__ size_in,
                                                  const void* __restrict__ mask_raw,
                                                  const int* __restrict__ flags,
                                                  bf16* __restrict__ xb,
                                                  bf16* __restrict__ wqb,
                                                  bf16* __restrict__ wpb,
                                                  float* __restrict__ biasb) {
  const int tid = blockIdx.x * 256 + threadIdx.x;   // 2048*256 = 524288 thr
  if (tid < B_ * N_) {
    int mv;
    if (flags[0]) {
      mv = (int)((const unsigned char*)mask_raw)[tid];
    } else if (flags[1]) {
      mv = ((const int*)mask_raw)[tid];
    } else {  // int64
      const unsigned* m32 = (const unsigned*)mask_raw;
      mv = (int)(m32[2 * tid] | m32[2 * tid + 1]);
    }
    biasb[tid] = mv ? -1e30f : logf(size_in[tid]);
  }
  for (int i = tid; i < 2162688; i += 524288) {
    const float* src;
    bf16* dst;
    int j = i;
    if (j < 1572864) {
      src = x; dst = xb;
    } else if (j < 2015232) {
      j -= 1572864; src = wq; dst = wqb;
    } else {
      j -= 2015232; src = wp; dst = wpb;
    }
    const float4 v = ((const float4*)src)[j];
    bf16x4 o = {(bf16)v.x, (bf16)v.y, (bf16)v.z, (bf16)v.w};
    ((bf16x4*)dst)[j] = o;
  }
}

// ---------------------------------------------------------------------------
// GEMM (NT): out[m][o] = sum_k A[m][k] * W[o][k].  M=8192, K=768.
// R23-best: 128x128 tile, BK=64, two LDS buffers (64KB -> 2 blocks/CU),
// 2-deep counted-vmcnt pipeline + s_setprio around the MFMA cluster.
// XOR bank swizzle both tiles (measured SQ_LDS_BANK_CONFLICT = 0).
// MODE 0: A linear [m][768]; scatter epilogue into q/k/vt
// MODE 1: A in [b][h][n][64] layout (attnw); f32 epilogue outf = acc + bias
// ---------------------------------------------------------------------------
template <int MODE>
__global__ __launch_bounds__(256) void gemm_bt(const bf16* __restrict__ A,
                                               const bf16* __restrict__ W,
                                               const float* __restrict__ bias,
                                               bf16* __restrict__ out0,
                                               bf16* __restrict__ out1,
                                               bf16* __restrict__ out2,
                                               float* __restrict__ outf) {
  __shared__ bf16 As[2][128 * 64];
  __shared__ bf16 Bs[2][128 * 64];
  const int bid = blockIdx.x;
  const int mt = bid % 64;
  const int nt = bid / 64;
  const int t = threadIdx.x;
  const int lane = t & 63, w = t >> 6;
  const int wm = w >> 1, wn = w & 1;
  const int l15 = lane & 15, lg = lane >> 4;

  f32x4 acc[4][4] = {};

  const int srow = t >> 3;                        // row within 32-row chunk
  const int skel = ((t & 7) ^ (srow & 7)) * 8;    // pre-swizzled source slot
  const bf16* Ag = A + (size_t)(mt * 128) * KDIM;
  const bf16* Bg = W + (size_t)(nt * 128) * KDIM;
  const int bA = mt >> 3;              // MODE 1: batch of this M-tile
  const int nbase = (mt & 7) * 128;    // MODE 1: n-base of this M-tile

#define ASRC(st, c)                                                          \
  ((MODE == 0)                                                               \
       ? (Ag + (size_t)((c) * 32 + srow) * KDIM + (st) * 64 + skel)          \
       : (A + (((size_t)(bA * 12 + (st)) * 1024) + nbase + (c) * 32 + srow)  \
              * 64 + skel))
#define BSRC(st, c) (Bg + (size_t)((c) * 32 + srow) * KDIM + (st) * 64 + skel)

#define STAGE(st, buf)                                                        \
  {                                                                           \
    _Pragma("unroll") for (int c = 0; c < 4; ++c) {                           \
      gload_lds16(ASRC(st, c), (char*)As[buf] + c * 4096 + w * 1024);         \
      gload_lds16(BSRC(st, c), (char*)Bs[buf] + c * 4096 + w * 1024);         \
    }                                                                         \
  }

  STAGE(0, 0);
  STAGE(1, 1);
  asm volatile("s_waitcnt vmcnt(8)" ::: "memory");
  __builtin_amdgcn_s_barrier();

  const int swz = l15 & 7;   // reader-side swizzle (row&7 == l15&7)

  for (int kt = 0; kt < KDIM / 64; ++kt) {
    const int cur = kt & 1;
    __builtin_amdgcn_s_setprio(1);
#pragma unroll
    for (int ks = 0; ks < 2; ++ks) {
      bf16x8 af[4], bfr[4];
#pragma unroll
      for (int i = 0; i < 4; ++i)
        af[i] = *(const bf16x8*)(As[cur] + (wm * 64 + i * 16 + l15) * 64 +
                                 ((ks * 4 + lg) ^ swz) * 8);
#pragma unroll
      for (int i = 0; i < 4; ++i)
        bfr[i] = *(const bf16x8*)(Bs[cur] + (wn * 64 + i * 16 + l15) * 64 +
                                  ((ks * 4 + lg) ^ swz) * 8);
#pragma unroll
      for (int i = 0; i < 4; ++i)
#pragma unroll
        for (int j = 0; j < 4; ++j)
          acc[i][j] = MFMA_16x16x32(af[i], bfr[j], acc[i][j]);
    }
    __builtin_amdgcn_s_setprio(0);
    __builtin_amdgcn_s_barrier();   // all waves done reading buf[cur]
    if (kt < KDIM / 64 - 2) {
      STAGE(kt + 2, cur);                               // 16 in flight
      asm volatile("s_waitcnt vmcnt(8)" ::: "memory");  // tile kt+1 landed
    } else {
      asm volatile("s_waitcnt vmcnt(0)" ::: "memory");  // tail drain
    }
    __builtin_amdgcn_s_barrier();   // tile kt+1 visible to all threads
  }
#undef STAGE
#undef ASRC
#undef BSRC

  if (MODE == 0) {
    const int which = (nt * 128) / 768;  // 768 = 6*128, tiles never straddle
#pragma unroll
    for (int i = 0; i < 4; ++i)
#pragma unroll
      for (int j = 0; j < 4; ++j)
#pragma unroll
        for (int r = 0; r < 4; ++r) {
          const int m = mt * 128 + wm * 64 + i * 16 + lg * 4 + r;
          const int o = nt * 128 + wn * 64 + j * 16 + l15;
          const int b = m >> 10, n = m & 1023;
          const int f = o - which * 768;
          const int h = f >> 6, hd = f & 63;
          const bf16 bv = (bf16)acc[i][j][r];
          if (which == 0)
            out0[(((size_t)(b * 12 + h)) * 1024 + n) * 64 + hd] = bv;
          else if (which == 1)
            out1[(((size_t)(b * 12 + h)) * 1024 + n) * 64 + hd] = bv;
          else
            out2[(((size_t)(b * 12 + h)) * 64 + hd) * 1024 + n] = bv;
        }
  } else {
#pragma unroll
    for (int i = 0; i < 4; ++i)
#pragma unroll
      for (int j = 0; j < 4; ++j) {
        const int o = nt * 128 + wn * 64 + j * 16 + l15;
        const float bv = bias[o];
#pragma unroll
        for (int r = 0; r < 4; ++r) {
          const int m = mt * 128 + wm * 64 + i * 16 + lg * 4 + r;
          outf[(size_t)m * 768 + o] = acc[i][j][r] + bv;
        }
      }
  }
}

// ---------------------------------------------------------------------------
// k_mean (f32 out): kmean[b,n,hd] = mean_h k[b,h,n,hd]
// ---------------------------------------------------------------------------
__global__ __launch_bounds__(256) void kmean_kernel(const bf16* __restrict__ kbuf,
                                                    float* __restrict__ kmean) {
  const int i = blockIdx.x * 256 + threadIdx.x;
  if (i >= B_ * N_ * HD_) return;
  const int hd = i & 63;
  const int n = (i >> 6) & 1023;
  const int b = i >> 16;
  float s = 0.f;
#pragma unroll
  for (int h = 0; h < 12; ++h)
    s += (float)kbuf[(((size_t)(b * 12 + h)) * 1024 + n) * 64 + hd];
  kmean[i] = s * (1.0f / 12.0f);
}

// ---------------------------------------------------------------------------
// MFMA flash attention. Block = 8 waves (512 thr), each wave 2 q-tiles of 16
// rows -> 256 q-rows/block; grid = 96 bh x 4 qt (FETCH floor ~111MB,
// mapping-independent). R24: R21-style 2-deep counted-vmcnt staging pipeline
// (STAGE kt+2 after the read-barrier; s_waitcnt vmcnt(2) = tile kt+1 landed;
// never drain mid-loop) + s_setprio around the MFMA clusters (4 co-resident
// blocks at independent phases). Swapped-operand QK^T, lane-local softmax,
// contiguous [b][h][n][64] store.
// ---------------------------------------------------------------------------
__global__ __launch_bounds__(512, 4) void attn_mfma(const bf16* __restrict__ qbuf,
                                                    const bf16* __restrict__ kbuf,
                                                    const bf16* __restrict__ vtbuf,
                                                    const float* __restrict__ biasb,
                                                    bf16* __restrict__ outws) {
  __shared__ bf16 Ks[2][4096];  // [64 rows][8 slots of 8 elems], swizzled
  __shared__ bf16 Vs[2][4096];
  const int id = blockIdx.x;
  const int qt = id & 3;
  const int bh = id >> 2;
  const int b = bh / 12;
  const int t = threadIdx.x, lane = t & 63, w = t >> 6;  // w 0..7
  const int l15 = lane & 15, lg = lane >> 4;
  const int qbase = qt * 256 + w * 16;   // tile0 rows; tile1 = qbase + 128

  const bf16* Q = qbuf + ((size_t)bh * 1024 + qbase) * 64;
  const bf16* Kp = kbuf + (size_t)bh * 65536;
  const bf16* Vt = vtbuf + (size_t)bh * 65536;
  const float* bias = biasb + b * 1024;

  // Q as B-operand: col=l15 (q-row), k-slots lg*8+e = d
  const bf16x8 qb0 = *(const bf16x8*)(Q + l15 * 64 + lg * 8);
  const bf16x8 qb1 = *(const bf16x8*)(Q + l15 * 64 + 32 + lg * 8);
  const bf16x8 qc0 = *(const bf16x8*)(Q + (128 + l15) * 64 + lg * 8);
  const bf16x8 qc1 = *(const bf16x8*)(Q + (128 + l15) * 64 + 32 + lg * 8);

  // staging: thread t fills LDS bytes [t*16, t*16+16) of each 8KB tile.
  // K row srow holds key pi(srow); phys slot (t&7) holds logical slot
  // (t&7)^(srow&7)  (bank swizzle via pre-swizzled source).
  const int srow = t >> 3;                 // 0..63
  const int dsl = (t & 7) ^ (srow & 7);
  const int kkey = 32 * ((srow >> 5) & 1) + 4 * ((srow >> 4) & 1) +
                   8 * ((srow >> 2) & 3) + (srow & 3);
  const bf16* srcK = Kp + kkey * 64 + dsl * 8;
  const bf16* srcV = Vt + (size_t)srow * 1024 + dsl * 8;

  // stage K/V tile kt into buffer buf (2 loads/thread)
#define ASTAGE(kt_, buf_)                                                     \
  {                                                                           \
    gload_lds16(srcK + (size_t)(kt_) * 4096, (char*)&Ks[buf_][0] + w * 1024); \
    gload_lds16(srcV + (kt_) * 64, (char*)&Vs[buf_][0] + w * 1024);           \
  }

  // prologue: tiles 0,1 in flight (4 loads); wait for tile 0 only
  ASTAGE(0, 0);
  ASTAGE(1, 1);
  asm volatile("s_waitcnt vmcnt(2)" ::: "memory");
  __builtin_amdgcn_s_barrier();

  const int bb0 = 8 * lg;        // bias quad base (D-row=lg*4+j)
  const int swz = l15 & 7;

  f32x4 oacc[4] = {}, oacc2[4] = {};
  float m = -1e30f, l = 0.f;
  float m2 = -1e30f, l2 = 0.f;

  for (int kt = 0; kt < 16; ++kt) {
    const int cur = kt & 1;
    const int kb = kt * 64;

    const bf16* LK = Ks[cur];
    const bf16* LV = Vs[cur];
    float sv[4][4], sw[4][4];
    __builtin_amdgcn_s_setprio(1);
#pragma unroll
    for (int f = 0; f < 4; ++f) {
      const int cf = 32 * (f >> 1) + 4 * (f & 1);
      const bf16* kj = LK + (f * 16 + l15) * 64;
      const bf16x8 ka0 = *(const bf16x8*)(kj + (lg ^ swz) * 8);
      const bf16x8 ka1 = *(const bf16x8*)(kj + ((lg + 4) ^ swz) * 8);
      f32x4 z = {}, y = {};
      z = MFMA_16x16x32(ka0, qb0, z);
      y = MFMA_16x16x32(ka0, qc0, y);
      z = MFMA_16x16x32(ka1, qb1, z);
      y = MFMA_16x16x32(ka1, qc1, y);
      const float4 bi = *(const float4*)(bias + kb + cf + bb0);
      sv[f][0] = z[0] * 0.125f + bi.x;
      sv[f][1] = z[1] * 0.125f + bi.y;
      sv[f][2] = z[2] * 0.125f + bi.z;
      sv[f][3] = z[3] * 0.125f + bi.w;
      sw[f][0] = y[0] * 0.125f + bi.x;
      sw[f][1] = y[1] * 0.125f + bi.y;
      sw[f][2] = y[2] * 0.125f + bi.z;
      sw[f][3] = y[3] * 0.125f + bi.w;
    }
    __builtin_amdgcn_s_setprio(0);
    // per-tile max over 64 keys: 15 local + 2 shuffles each
    float mx = sv[0][0], mx2 = sw[0][0];
#pragma unroll
    for (int f = 0; f < 4; ++f)
#pragma unroll
      for (int j = 0; j < 4; ++j) {
        mx = fmaxf(mx, sv[f][j]);
        mx2 = fmaxf(mx2, sw[f][j]);
      }
    mx = fmaxf(mx, __shfl_xor(mx, 16, 64));
    mx = fmaxf(mx, __shfl_xor(mx, 32, 64));
    mx2 = fmaxf(mx2, __shfl_xor(mx2, 16, 64));
    mx2 = fmaxf(mx2, __shfl_xor(mx2, 32, 64));
    const float mn = fmaxf(m, mx);
    const float mn2 = fmaxf(m2, mx2);
    const float resc = __expf(m - mn);
    const float resc2 = __expf(m2 - mn2);
    m = mn;
    m2 = mn2;

    float rs = 0.f, rs2 = 0.f;
    bf16x8 pa0, pa1, pa2, pa3;
#pragma unroll
    for (int f = 0; f < 4; ++f)
#pragma unroll
      for (int j = 0; j < 4; ++j) {
        const float p = __expf(sv[f][j] - mn);
        const float p2 = __expf(sw[f][j] - mn2);
        rs += p;
        rs2 += p2;
        const bf16 pb = (bf16)p;
        const bf16 pb2 = (bf16)p2;
        if (f == 0) { pa0[j] = pb; pa2[j] = pb2; }
        else if (f == 1) { pa0[4 + j] = pb; pa2[4 + j] = pb2; }
        else if (f == 2) { pa1[j] = pb; pa3[j] = pb2; }
        else { pa1[4 + j] = pb; pa3[4 + j] = pb2; }
      }
    rs += __shfl_xor(rs, 16, 64);
    rs += __shfl_xor(rs, 32, 64);
    rs2 += __shfl_xor(rs2, 16, 64);
    rs2 += __shfl_xor(rs2, 32, 64);
    l = l * resc + rs;
    l2 = l2 * resc2 + rs2;

    __builtin_amdgcn_s_setprio(1);
#pragma unroll
    for (int df = 0; df < 4; ++df) {
      const bf16* vj = LV + (df * 16 + l15) * 64;
      const bf16x8 va0 = *(const bf16x8*)(vj + (lg ^ swz) * 8);
      const bf16x8 va1 = *(const bf16x8*)(vj + ((lg + 4) ^ swz) * 8);
      f32x4 t4 = oacc[df];
      f32x4 u4 = oacc2[df];
#pragma unroll
      for (int j = 0; j < 4; ++j) {
        t4[j] *= resc;
        u4[j] *= resc2;
      }
      t4 = MFMA_16x16x32(va0, pa0, t4);
      u4 = MFMA_16x16x32(va0, pa2, u4);
      t4 = MFMA_16x16x32(va1, pa1, t4);
      u4 = MFMA_16x16x32(va1, pa3, u4);
      oacc[df] = t4;
      oacc2[df] = u4;
    }
    __builtin_amdgcn_s_setprio(0);

    __builtin_amdgcn_s_barrier();   // all waves done reading buf[cur]
    if (kt < 14) {
      ASTAGE(kt + 2, cur);                              // 4 in flight
      asm volatile("s_waitcnt vmcnt(2)" ::: "memory");  // tile kt+1 landed
    } else {
      asm volatile("s_waitcnt vmcnt(0)" ::: "memory");  // tail drain
    }
    __builtin_amdgcn_s_barrier();   // tile kt+1 visible to all threads
  }
#undef ASTAGE

  // contiguous store: attnw[b][h][n][64]; tile0 rows qbase.., tile1 +128
  const float inv = 1.0f / l;
  const float inv2 = 1.0f / l2;
  bf16* outp = outws + ((size_t)bh * 1024 + qbase + l15) * 64;
#pragma unroll
  for (int df = 0; df < 4; ++df) {
    bf16x4 ov = {(bf16)(oacc[df][0] * inv), (bf16)(oacc[df][1] * inv),
                 (bf16)(oacc[df][2] * inv), (bf16)(oacc[df][3] * inv)};
    *(bf16x4*)(outp + df * 16 + lg * 4) = ov;
    bf16x4 ov2 = {(bf16)(oacc2[df][0] * inv2), (bf16)(oacc2[df][1] * inv2),
                  (bf16)(oacc2[df][2] * inv2), (bf16)(oacc2[df][3] * inv2)};
    *(bf16x4*)(outp + (size_t)128 * 64 + df * 16 + lg * 4) = ov2;
  }
}

// ---------------------------------------------------------------------------
extern "C" void kernel_launch(void* const* d_in, const int* in_sizes, int n_in,
                              void* d_out, int out_size, void* d_ws, size_t ws_size,
                              hipStream_t stream) {
  const float* x       = (const float*)d_in[0];
  const float* size_in = (const float*)d_in[1];
  const void*  mask    = d_in[2];
  const float* w_qkv   = (const float*)d_in[3];
  const float* w_proj  = (const float*)d_in[4];
  const float* b_proj  = (const float*)d_in[5];
  float* out = (float*)d_out;   // f32 outputs per reference dtype

  if (n_in < 6 ||
      in_sizes[0] != 6291456 || in_sizes[1] != 8192 || in_sizes[2] != 8192 ||
      in_sizes[3] != 1769472 || in_sizes[4] != 589824 || in_sizes[5] != 768)
    return;

  const size_t QS = (size_t)B_ * H_ * N_ * HD_;  // 6291456 elems
  if (ws_size < 55083024) return;

  bf16* xb    = (bf16*)d_ws;       // dead after gemm<0>; reused as attnw
  bf16* qbuf  = xb + QS;
  bf16* kbuf  = qbuf + QS;
  bf16* vtbuf = kbuf + QS;
  bf16* wqb   = vtbuf + QS;        // 1769472 elems
  bf16* wpb   = wqb + 1769472;     // 589824 elems
  float* biasb = (float*)(wpb + 589824);
  int* flags = (int*)(biasb + 8192);
  bf16* attnw = xb;                // [b][h][n][64]

  hipMemsetAsync(flags, 0, 8, stream);
  detect_mask_kernel<<<8, 256, 0, stream>>>((const unsigned*)mask, flags);
  cvt_kernel<<<2048, 256, 0, stream>>>(x, w_qkv, w_proj, size_in, mask, flags,
                                       xb, wqb, wpb, biasb);
  gemm_bt<0><<<64 * 18, 256, 0, stream>>>(xb, wqb, nullptr, qbuf, kbuf, vtbuf, nullptr);
  kmean_kernel<<<2048, 256, 0, stream>>>(kbuf, out + (size_t)B_ * N_ * C_);
  attn_mfma<<<384, 512, 0, stream>>>(qbuf, kbuf, vtbuf, biasb, attnw);
  gemm_bt<1><<<64 * 6, 256, 0, stream>>>(attnw, wpb, b_proj, nullptr, nullptr, nullptr, out);
}

// Round 25
// 145.810 us; speedup vs baseline: 1.1592x; 1.0346x over previous
//
#include <hip/hip_runtime.h>

typedef __bf16 bf16;
typedef __bf16 bf16x4 __attribute__((ext_vector_type(4)));
typedef __bf16 bf16x8 __attribute__((ext_vector_type(8)));
typedef float f32x4 __attribute__((ext_vector_type(4)));

#define MFMA_16x16x32(a, b, c) __builtin_amdgcn_mfma_f32_16x16x32_bf16((a), (b), (c), 0, 0, 0)

#define B_ 8
#define N_ 1024
#define C_ 768
#define H_ 12
#define HD_ 64
#define KDIM 768

__device__ __forceinline__ void gload_lds16(const void* g, void* l) {
  __builtin_amdgcn_global_load_lds(
      (const __attribute__((address_space(1))) void*)g,
      (__attribute__((address_space(3))) void*)l, 16, 0, 0);
}

// ---------------------------------------------------------------------------
// cvt (R25: mask-dtype detection inlined). f32 -> bf16 for x|wq|wp as one
// flat range of float4 jobs; bias on first 8192 global threads. Blocks 0-31
// self-detect mask storage (int8/int32/int64) by scanning its first 8KB
// into __shared__ flags -- removes the memset + detect dispatches.
// ---------------------------------------------------------------------------
__global__ __launch_bounds__(256) void cvt_kernel(const float* __restrict__ x,
                                                  const float* __restrict__ wq,
                                                  const float* __restrict__ wp,
                                                  const float* __restrict__ size_in,
                                                  const void* __restrict__ mask_raw,
                                                  bf16* __restrict__ xb,
                                                  bf16* __restrict__ wqb,
                                                  bf16* __restrict__ wpb,
                                                  float* __restrict__ biasb) {
  const int tid = blockIdx.x * 256 + threadIdx.x;   // 2048*256 = 524288 thr
  if (blockIdx.x < 32) {
    __shared__ int sflags[2];
    if (threadIdx.x < 2) sflags[threadIdx.x] = 0;
    __syncthreads();
    const unsigned* m32 = (const unsigned*)mask_raw;
    int f0 = 0, f1 = 0;
#pragma unroll
    for (int k = 0; k < 8; ++k) {
      const int idx = threadIdx.x * 8 + k;  // 0..2047 (first 8KB)
      const unsigned v = m32[idx];
      if (v > 1u) f0 = 1;                   // byte-packed (int8/bool)
      if ((idx & 1) && v != 0u) f1 = 1;     // odd word nonzero -> int32
    }
    if (f0) atomicOr(&sflags[0], 1);
    if (f1) atomicOr(&sflags[1], 1);
    __syncthreads();
    if (tid < B_ * N_) {
      int mv;
      if (sflags[0]) {
        mv = (int)((const unsigned char*)mask_raw)[tid];
      } else if (sflags[1]) {
        mv = ((const int*)mask_raw)[tid];
      } else {  // int64
        mv = (int)(m32[2 * tid] | m32[2 * tid + 1]);
      }
      biasb[tid] = mv ? -1e30f : logf(size_in[tid]);
    }
  }
  for (int i = tid; i < 2162688; i += 524288) {
    const float* src;
    bf16* dst;
    int j = i;
    if (j < 1572864) {
      src = x; dst = xb;
    } else if (j < 2015232) {
      j -= 1572864; src = wq; dst = wqb;
    } else {
      j -= 2015232; src = wp; dst = wpb;
    }
    const float4 v = ((const float4*)src)[j];
    bf16x4 o = {(bf16)v.x, (bf16)v.y, (bf16)v.z, (bf16)v.w};
    ((bf16x4*)dst)[j] = o;
  }
}

// ---------------------------------------------------------------------------
// GEMM (NT): out[m][o] = sum_k A[m][k] * W[o][k].  M=8192, K=768.
// R23-best: 128x128 tile, BK=64, two LDS buffers (64KB -> 2 blocks/CU),
// 2-deep counted-vmcnt pipeline + s_setprio around the MFMA cluster.
// XOR bank swizzle both tiles (measured SQ_LDS_BANK_CONFLICT = 0).
// MODE 0: A linear [m][768]; scatter epilogue into q/k/vt
// MODE 1: A in [b][h][n][64] layout (attnw); f32 epilogue outf = acc + bias
// ---------------------------------------------------------------------------
template <int MODE>
__global__ __launch_bounds__(256) void gemm_bt(const bf16* __restrict__ A,
                                               const bf16* __restrict__ W,
                                               const float* __restrict__ bias,
                                               bf16* __restrict__ out0,
                                               bf16* __restrict__ out1,
                                               bf16* __restrict__ out2,
                                               float* __restrict__ outf) {
  __shared__ bf16 As[2][128 * 64];
  __shared__ bf16 Bs[2][128 * 64];
  const int bid = blockIdx.x;
  const int mt = bid % 64;
  const int nt = bid / 64;
  const int t = threadIdx.x;
  const int lane = t & 63, w = t >> 6;
  const int wm = w >> 1, wn = w & 1;
  const int l15 = lane & 15, lg = lane >> 4;

  f32x4 acc[4][4] = {};

  const int srow = t >> 3;                        // row within 32-row chunk
  const int skel = ((t & 7) ^ (srow & 7)) * 8;    // pre-swizzled source slot
  const bf16* Ag = A + (size_t)(mt * 128) * KDIM;
  const bf16* Bg = W + (size_t)(nt * 128) * KDIM;
  const int bA = mt >> 3;              // MODE 1: batch of this M-tile
  const int nbase = (mt & 7) * 128;    // MODE 1: n-base of this M-tile

#define ASRC(st, c)                                                          \
  ((MODE == 0)                                                               \
       ? (Ag + (size_t)((c) * 32 + srow) * KDIM + (st) * 64 + skel)          \
       : (A + (((size_t)(bA * 12 + (st)) * 1024) + nbase + (c) * 32 + srow)  \
              * 64 + skel))
#define BSRC(st, c) (Bg + (size_t)((c) * 32 + srow) * KDIM + (st) * 64 + skel)

#define STAGE(st, buf)                                                        \
  {                                                                           \
    _Pragma("unroll") for (int c = 0; c < 4; ++c) {                           \
      gload_lds16(ASRC(st, c), (char*)As[buf] + c * 4096 + w * 1024);         \
      gload_lds16(BSRC(st, c), (char*)Bs[buf] + c * 4096 + w * 1024);         \
    }                                                                         \
  }

  STAGE(0, 0);
  STAGE(1, 1);
  asm volatile("s_waitcnt vmcnt(8)" ::: "memory");
  __builtin_amdgcn_s_barrier();

  const int swz = l15 & 7;   // reader-side swizzle (row&7 == l15&7)

  for (int kt = 0; kt < KDIM / 64; ++kt) {
    const int cur = kt & 1;
    __builtin_amdgcn_s_setprio(1);
#pragma unroll
    for (int ks = 0; ks < 2; ++ks) {
      bf16x8 af[4], bfr[4];
#pragma unroll
      for (int i = 0; i < 4; ++i)
        af[i] = *(const bf16x8*)(As[cur] + (wm * 64 + i * 16 + l15) * 64 +
                                 ((ks * 4 + lg) ^ swz) * 8);
#pragma unroll
      for (int i = 0; i < 4; ++i)
        bfr[i] = *(const bf16x8*)(Bs[cur] + (wn * 64 + i * 16 + l15) * 64 +
                                  ((ks * 4 + lg) ^ swz) * 8);
#pragma unroll
      for (int i = 0; i < 4; ++i)
#pragma unroll
        for (int j = 0; j < 4; ++j)
          acc[i][j] = MFMA_16x16x32(af[i], bfr[j], acc[i][j]);
    }
    __builtin_amdgcn_s_setprio(0);
    __builtin_amdgcn_s_barrier();   // all waves done reading buf[cur]
    if (kt < KDIM / 64 - 2) {
      STAGE(kt + 2, cur);                               // 16 in flight
      asm volatile("s_waitcnt vmcnt(8)" ::: "memory");  // tile kt+1 landed
    } else {
      asm volatile("s_waitcnt vmcnt(0)" ::: "memory");  // tail drain
    }
    __builtin_amdgcn_s_barrier();   // tile kt+1 visible to all threads
  }
#undef STAGE
#undef ASRC
#undef BSRC

  if (MODE == 0) {
    const int which = (nt * 128) / 768;  // 768 = 6*128, tiles never straddle
#pragma unroll
    for (int i = 0; i < 4; ++i)
#pragma unroll
      for (int j = 0; j < 4; ++j)
#pragma unroll
        for (int r = 0; r < 4; ++r) {
          const int m = mt * 128 + wm * 64 + i * 16 + lg * 4 + r;
          const int o = nt * 128 + wn * 64 + j * 16 + l15;
          const int b = m >> 10, n = m & 1023;
          const int f = o - which * 768;
          const int h = f >> 6, hd = f & 63;
          const bf16 bv = (bf16)acc[i][j][r];
          if (which == 0)
            out0[(((size_t)(b * 12 + h)) * 1024 + n) * 64 + hd] = bv;
          else if (which == 1)
            out1[(((size_t)(b * 12 + h)) * 1024 + n) * 64 + hd] = bv;
          else
            out2[(((size_t)(b * 12 + h)) * 64 + hd) * 1024 + n] = bv;
        }
  } else {
#pragma unroll
    for (int i = 0; i < 4; ++i)
#pragma unroll
      for (int j = 0; j < 4; ++j) {
        const int o = nt * 128 + wn * 64 + j * 16 + l15;
        const float bv = bias[o];
#pragma unroll
        for (int r = 0; r < 4; ++r) {
          const int m = mt * 128 + wm * 64 + i * 16 + lg * 4 + r;
          outf[(size_t)m * 768 + o] = acc[i][j][r] + bv;
        }
      }
  }
}

// ---------------------------------------------------------------------------
// k_mean (f32 out): kmean[b,n,hd] = mean_h k[b,h,n,hd]
// ---------------------------------------------------------------------------
__global__ __launch_bounds__(256) void kmean_kernel(const bf16* __restrict__ kbuf,
                                                    float* __restrict__ kmean) {
  const int i = blockIdx.x * 256 + threadIdx.x;
  if (i >= B_ * N_ * HD_) return;
  const int hd = i & 63;
  const int n = (i >> 6) & 1023;
  const int b = i >> 16;
  float s = 0.f;
#pragma unroll
  for (int h = 0; h < 12; ++h)
    s += (float)kbuf[(((size_t)(b * 12 + h)) * 1024 + n) * 64 + hd];
  kmean[i] = s * (1.0f / 12.0f);
}

// ---------------------------------------------------------------------------
// MFMA flash attention (R24-validated). Block = 8 waves (512 thr), each wave
// 2 q-tiles of 16 rows -> 256 q-rows/block; grid = 96 bh x 4 qt (FETCH floor
// ~111MB, mapping-independent). 2-deep counted-vmcnt staging pipeline +
// s_setprio around MFMA clusters. Swapped-operand QK^T, lane-local softmax,
// contiguous [b][h][n][64] store.
// ---------------------------------------------------------------------------
__global__ __launch_bounds__(512, 4) void attn_mfma(const bf16* __restrict__ qbuf,
                                                    const bf16* __restrict__ kbuf,
                                                    const bf16* __restrict__ vtbuf,
                                                    const float* __restrict__ biasb,
                                                    bf16* __restrict__ outws) {
  __shared__ bf16 Ks[2][4096];  // [64 rows][8 slots of 8 elems], swizzled
  __shared__ bf16 Vs[2][4096];
  const int id = blockIdx.x;
  const int qt = id & 3;
  const int bh = id >> 2;
  const int b = bh / 12;
  const int t = threadIdx.x, lane = t & 63, w = t >> 6;  // w 0..7
  const int l15 = lane & 15, lg = lane >> 4;
  const int qbase = qt * 256 + w * 16;   // tile0 rows; tile1 = qbase + 128

  const bf16* Q = qbuf + ((size_t)bh * 1024 + qbase) * 64;
  const bf16* Kp = kbuf + (size_t)bh * 65536;
  const bf16* Vt = vtbuf + (size_t)bh * 65536;
  const float* bias = biasb + b * 1024;

  // Q as B-operand: col=l15 (q-row), k-slots lg*8+e = d
  const bf16x8 qb0 = *(const bf16x8*)(Q + l15 * 64 + lg * 8);
  const bf16x8 qb1 = *(const bf16x8*)(Q + l15 * 64 + 32 + lg * 8);
  const bf16x8 qc0 = *(const bf16x8*)(Q + (128 + l15) * 64 + lg * 8);
  const bf16x8 qc1 = *(const bf16x8*)(Q + (128 + l15) * 64 + 32 + lg * 8);

  // staging: thread t fills LDS bytes [t*16, t*16+16) of each 8KB tile.
  // K row srow holds key pi(srow); phys slot (t&7) holds logical slot
  // (t&7)^(srow&7)  (bank swizzle via pre-swizzled source).
  const int srow = t >> 3;                 // 0..63
  const int dsl = (t & 7) ^ (srow & 7);
  const int kkey = 32 * ((srow >> 5) & 1) + 4 * ((srow >> 4) & 1) +
                   8 * ((srow >> 2) & 3) + (srow & 3);
  const bf16* srcK = Kp + kkey * 64 + dsl * 8;
  const bf16* srcV = Vt + (size_t)srow * 1024 + dsl * 8;

#define ASTAGE(kt_, buf_)                                                     \
  {                                                                           \
    gload_lds16(srcK + (size_t)(kt_) * 4096, (char*)&Ks[buf_][0] + w * 1024); \
    gload_lds16(srcV + (kt_) * 64, (char*)&Vs[buf_][0] + w * 1024);           \
  }

  ASTAGE(0, 0);
  ASTAGE(1, 1);
  asm volatile("s_waitcnt vmcnt(2)" ::: "memory");
  __builtin_amdgcn_s_barrier();

  const int bb0 = 8 * lg;        // bias quad base (D-row=lg*4+j)
  const int swz = l15 & 7;

  f32x4 oacc[4] = {}, oacc2[4] = {};
  float m = -1e30f, l = 0.f;
  float m2 = -1e30f, l2 = 0.f;

  for (int kt = 0; kt < 16; ++kt) {
    const int cur = kt & 1;
    const int kb = kt * 64;

    const bf16* LK = Ks[cur];
    const bf16* LV = Vs[cur];
    float sv[4][4], sw[4][4];
    __builtin_amdgcn_s_setprio(1);
#pragma unroll
    for (int f = 0; f < 4; ++f) {
      const int cf = 32 * (f >> 1) + 4 * (f & 1);
      const bf16* kj = LK + (f * 16 + l15) * 64;
      const bf16x8 ka0 = *(const bf16x8*)(kj + (lg ^ swz) * 8);
      const bf16x8 ka1 = *(const bf16x8*)(kj + ((lg + 4) ^ swz) * 8);
      f32x4 z = {}, y = {};
      z = MFMA_16x16x32(ka0, qb0, z);
      y = MFMA_16x16x32(ka0, qc0, y);
      z = MFMA_16x16x32(ka1, qb1, z);
      y = MFMA_16x16x32(ka1, qc1, y);
      const float4 bi = *(const float4*)(bias + kb + cf + bb0);
      sv[f][0] = z[0] * 0.125f + bi.x;
      sv[f][1] = z[1] * 0.125f + bi.y;
      sv[f][2] = z[2] * 0.125f + bi.z;
      sv[f][3] = z[3] * 0.125f + bi.w;
      sw[f][0] = y[0] * 0.125f + bi.x;
      sw[f][1] = y[1] * 0.125f + bi.y;
      sw[f][2] = y[2] * 0.125f + bi.z;
      sw[f][3] = y[3] * 0.125f + bi.w;
    }
    __builtin_amdgcn_s_setprio(0);
    // per-tile max over 64 keys: 15 local + 2 shuffles each
    float mx = sv[0][0], mx2 = sw[0][0];
#pragma unroll
    for (int f = 0; f < 4; ++f)
#pragma unroll
      for (int j = 0; j < 4; ++j) {
        mx = fmaxf(mx, sv[f][j]);
        mx2 = fmaxf(mx2, sw[f][j]);
      }
    mx = fmaxf(mx, __shfl_xor(mx, 16, 64));
    mx = fmaxf(mx, __shfl_xor(mx, 32, 64));
    mx2 = fmaxf(mx2, __shfl_xor(mx2, 16, 64));
    mx2 = fmaxf(mx2, __shfl_xor(mx2, 32, 64));
    const float mn = fmaxf(m, mx);
    const float mn2 = fmaxf(m2, mx2);
    const float resc = __expf(m - mn);
    const float resc2 = __expf(m2 - mn2);
    m = mn;
    m2 = mn2;

    float rs = 0.f, rs2 = 0.f;
    bf16x8 pa0, pa1, pa2, pa3;
#pragma unroll
    for (int f = 0; f < 4; ++f)
#pragma unroll
      for (int j = 0; j < 4; ++j) {
        const float p = __expf(sv[f][j] - mn);
        const float p2 = __expf(sw[f][j] - mn2);
        rs += p;
        rs2 += p2;
        const bf16 pb = (bf16)p;
        const bf16 pb2 = (bf16)p2;
        if (f == 0) { pa0[j] = pb; pa2[j] = pb2; }
        else if (f == 1) { pa0[4 + j] = pb; pa2[4 + j] = pb2; }
        else if (f == 2) { pa1[j] = pb; pa3[j] = pb2; }
        else { pa1[4 + j] = pb; pa3[4 + j] = pb2; }
      }
    rs += __shfl_xor(rs, 16, 64);
    rs += __shfl_xor(rs, 32, 64);
    rs2 += __shfl_xor(rs2, 16, 64);
    rs2 += __shfl_xor(rs2, 32, 64);
    l = l * resc + rs;
    l2 = l2 * resc2 + rs2;

    __builtin_amdgcn_s_setprio(1);
#pragma unroll
    for (int df = 0; df < 4; ++df) {
      const bf16* vj = LV + (df * 16 + l15) * 64;
      const bf16x8 va0 = *(const bf16x8*)(vj + (lg ^ swz) * 8);
      const bf16x8 va1 = *(const bf16x8*)(vj + ((lg + 4) ^ swz) * 8);
      f32x4 t4 = oacc[df];
      f32x4 u4 = oacc2[df];
#pragma unroll
      for (int j = 0; j < 4; ++j) {
        t4[j] *= resc;
        u4[j] *= resc2;
      }
      t4 = MFMA_16x16x32(va0, pa0, t4);
      u4 = MFMA_16x16x32(va0, pa2, u4);
      t4 = MFMA_16x16x32(va1, pa1, t4);
      u4 = MFMA_16x16x32(va1, pa3, u4);
      oacc[df] = t4;
      oacc2[df] = u4;
    }
    __builtin_amdgcn_s_setprio(0);

    __builtin_amdgcn_s_barrier();   // all waves done reading buf[cur]
    if (kt < 14) {
      ASTAGE(kt + 2, cur);                              // 4 in flight
      asm volatile("s_waitcnt vmcnt(2)" ::: "memory");  // tile kt+1 landed
    } else {
      asm volatile("s_waitcnt vmcnt(0)" ::: "memory");  // tail drain
    }
    __builtin_amdgcn_s_barrier();   // tile kt+1 visible to all threads
  }
#undef ASTAGE

  // contiguous store: attnw[b][h][n][64]; tile0 rows qbase.., tile1 +128
  const float inv = 1.0f / l;
  const float inv2 = 1.0f / l2;
  bf16* outp = outws + ((size_t)bh * 1024 + qbase + l15) * 64;
#pragma unroll
  for (int df = 0; df < 4; ++df) {
    bf16x4 ov = {(bf16)(oacc[df][0] * inv), (bf16)(oacc[df][1] * inv),
                 (bf16)(oacc[df][2] * inv), (bf16)(oacc[df][3] * inv)};
    *(bf16x4*)(outp + df * 16 + lg * 4) = ov;
    bf16x4 ov2 = {(bf16)(oacc2[df][0] * inv2), (bf16)(oacc2[df][1] * inv2),
                  (bf16)(oacc2[df][2] * inv2), (bf16)(oacc2[df][3] * inv2)};
    *(bf16x4*)(outp + (size_t)128 * 64 + df * 16 + lg * 4) = ov2;
  }
}

// ---------------------------------------------------------------------------
extern "C" void kernel_launch(void* const* d_in, const int* in_sizes, int n_in,
                              void* d_out, int out_size, void* d_ws, size_t ws_size,
                              hipStream_t stream) {
  const float* x       = (const float*)d_in[0];
  const float* size_in = (const float*)d_in[1];
  const void*  mask    = d_in[2];
  const float* w_qkv   = (const float*)d_in[3];
  const float* w_proj  = (const float*)d_in[4];
  const float* b_proj  = (const float*)d_in[5];
  float* out = (float*)d_out;   // f32 outputs per reference dtype

  if (n_in < 6 ||
      in_sizes[0] != 6291456 || in_sizes[1] != 8192 || in_sizes[2] != 8192 ||
      in_sizes[3] != 1769472 || in_sizes[4] != 589824 || in_sizes[5] != 768)
    return;

  const size_t QS = (size_t)B_ * H_ * N_ * HD_;  // 6291456 elems
  if (ws_size < 55083024) return;

  bf16* xb    = (bf16*)d_ws;       // dead after gemm<0>; reused as attnw
  bf16* qbuf  = xb + QS;
  bf16* kbuf  = qbuf + QS;
  bf16* vtbuf = kbuf + QS;
  bf16* wqb   = vtbuf + QS;        // 1769472 elems
  bf16* wpb   = wqb + 1769472;     // 589824 elems
  float* biasb = (float*)(wpb + 589824);
  bf16* attnw = xb;                // [b][h][n][64]

  cvt_kernel<<<2048, 256, 0, stream>>>(x, w_qkv, w_proj, size_in, mask,
                                       xb, wqb, wpb, biasb);
  gemm_bt<0><<<64 * 18, 256, 0, stream>>>(xb, wqb, nullptr, qbuf, kbuf, vtbuf, nullptr);
  kmean_kernel<<<2048, 256, 0, stream>>>(kbuf, out + (size_t)B_ * N_ * C_);
  attn_mfma<<<384, 512, 0, stream>>>(qbuf, kbuf, vtbuf, biasb, attnw);
  gemm_bt<1><<<64 * 6, 256, 0, stream>>>(attnw, wpb, b_proj, nullptr, nullptr, nullptr, out);
}